// Round 15
// baseline (298.240 us; speedup 1.0000x reference)
//
#include <hip/hip_runtime.h>
#include <hip/hip_bf16.h>
#include <hip/hip_fp16.h>
#include <math.h>

// Problem constants
#define NPTS 65536
#define DIM  256
#define KC   512

// som_main geometry
#define BM    128                 // points per block
#define NBLK  (NPTS / BM)         // 512 blocks
#define XSTR  264                 // x LDS row stride in halfs (528 B, 16B-aligned)
#define EPS   0.01f               // split-fp16 coarse err ~2e-5 -> huge margin (r9-proven)

// d_out layout (floats): [0]=loss, [1..1+16777216)=quantized, [16777217]=perplexity,
// [16777218..+65536)=enc_idx (as float)
#define QOFF  1
#define PIDX  16777217
#define EOFF  16777218

// d_ws layout:
//   wfh  _Float16[131072]  @ 0        (256 KB)  w hi, MFMA fragment order (ctg-major, r9)
//   wfl  _Float16[131072]  @ 262144   (256 KB)  w lo
//   wsq  float[512]        @ 524288
//   g    float[512]        @ 526336   (probe scratch after som_final consumes it)
//   hist int[512]          @ 528384
//   mse  double            @ 530432
// fragment order: off(c,k) = ((c>>4)*8 + (k>>5))*512 + ((k>>3)&3)*128 + (c&15)*8 + (k&7)

typedef _Float16 h8    __attribute__((ext_vector_type(8)));
typedef float    f32x4 __attribute__((ext_vector_type(4)));

__device__ inline void cvt_split8(float4 a, float4 b, h8& hv, h8& lv) {
    float f[8] = {a.x, a.y, a.z, a.w, b.x, b.y, b.z, b.w};
    #pragma unroll
    for (int i = 0; i < 8; ++i) {
        _Float16 h = (_Float16)f[i];
        hv[i] = h;
        lv[i] = (_Float16)(f[i] - (float)h);
    }
}

// merge top-2 set with another top-2 set; first-index tie-break on best (r5-verified)
__device__ inline void merge_top2(float& b1, int& i1, float& b2, int& i2,
                                  float ob1, int oi1, float ob2, int oi2) {
    bool ow = (ob1 < b1) || (ob1 == b1 && oi1 < i1);
    float lb = ow ? b1 : ob1; int li = ow ? i1 : oi1;
    if (ow) { b1 = ob1; i1 = oi1; }
    float c2 = b2; int ci = i2;
    if (ob2 < c2 || (ob2 == c2 && oi2 < ci)) { c2 = ob2; ci = oi2; }
    if (lb  < c2 || (lb  == c2 && li  < ci)) { c2 = lb;  ci = li;  }
    b2 = c2; i2 = ci;
}

// exact fp32 distance (same accumulation family as the r3-passing kernel)
__device__ inline float exact_dist(const float* __restrict__ xr,
                                   const float* __restrict__ w, int c, float wsqc) {
    const float* wr = w + (size_t)c * DIM;
    float d0 = 0.f, d1 = 0.f, d2 = 0.f, d3 = 0.f;
    #pragma unroll 4
    for (int d = 0; d < DIM; d += 4) {
        d0 = fmaf(xr[d + 0], wr[d + 0], d0);
        d1 = fmaf(xr[d + 1], wr[d + 1], d1);
        d2 = fmaf(xr[d + 2], wr[d + 2], d2);
        d3 = fmaf(xr[d + 3], wr[d + 3], d3);
    }
    return wsqc - 2.f * ((d0 + d1) + (d2 + d3));
}

// ---------------- wsq: |w_k|^2 (exact r3 order) + zero hist/mse ----------------
__global__ __launch_bounds__(256) void som_wsq(const float* __restrict__ w,
                                               float* __restrict__ wsq,
                                               int* __restrict__ hist,
                                               double* __restrict__ mse_acc)
{
    int k = blockIdx.x * 256 + threadIdx.x;   // grid = 2
    const float4* r = reinterpret_cast<const float4*>(w + (size_t)k * DIM);
    float s0 = 0.f, s1 = 0.f, s2 = 0.f, s3 = 0.f;
    #pragma unroll 8
    for (int q = 0; q < DIM / 4; ++q) {
        float4 v = r[q];
        s0 = fmaf(v.x, v.x, s0);
        s1 = fmaf(v.y, v.y, s1);
        s2 = fmaf(v.z, v.z, s2);
        s3 = fmaf(v.w, v.w, s3);
    }
    wsq[k] = (s0 + s1) + (s2 + s3);
    hist[k] = 0;
    if (k == 0) *mse_acc = 0.0;
}

// ---------------- conv: split-f16 conversion of w into fragment order (r9 layout) ----------------
__global__ __launch_bounds__(256) void som_conv(const float* __restrict__ w,
                                                _Float16* __restrict__ wfh,
                                                _Float16* __restrict__ wfl)
{
    const int tid = threadIdx.x;
    const int row = blockIdx.x * 8 + (tid >> 5);   // code row; grid = 64
    const int g   = tid & 31;                      // h8 unit within row
    const float4* r = reinterpret_cast<const float4*>(w + (size_t)row * DIM);
    float4 a = r[g * 2], b = r[g * 2 + 1];
    h8 hv, lv; cvt_split8(a, b, hv, lv);
    int dsl = g >> 2, kg = g & 3;
    int ctg = row >> 4, l15 = row & 15;
    size_t off = (((size_t)(ctg * 8 + dsl)) * 4 + kg) * 128 + l15 * 8;
    *reinterpret_cast<h8*>(wfh + off) = hv;
    *reinterpret_cast<h8*>(wfl + off) = lv;
}

// ---------------- main: split-fp16 MFMA argmin (byte-identical to r14, 125 us) ----------------
__global__ __launch_bounds__(1024) void som_main(const float* __restrict__ x,
                                                 const float* __restrict__ w,
                                                 const _Float16* __restrict__ wfh,
                                                 const _Float16* __restrict__ wfl,
                                                 float* __restrict__ out,
                                                 const float* __restrict__ wsq,
                                                 int* __restrict__ hist,
                                                 double* __restrict__ mse_acc)
{
    alignas(16) __shared__ _Float16 xh[BM * XSTR];   // 67,584 B
    alignas(16) __shared__ _Float16 xl[BM * XSTR];   // 67,584 B
    __shared__ float wsq_s[KC];                      // 2 KB
    __shared__ float xsq_s[BM];                      // 512 B
    __shared__ float wsum[2];

    // post-MFMA aliases (xh/xl are dead after the last B-read; barrier-protected)
    float* red_b  = reinterpret_cast<float*>(xh);            // [8][BM]
    float* red_s  = red_b + 8 * BM;                          // [8][BM]
    int*   red_ib = reinterpret_cast<int*>(red_s + 8 * BM);  // [8][BM]
    int*   red_is = red_ib + 8 * BM;                         // [8][BM]
    int*   bidx_s = reinterpret_cast<int*>(xl);              // [BM]

    const int tid  = threadIdx.x;
    const int lane = tid & 63;
    const int wid  = tid >> 6;        // 0..15
    const int l15  = lane & 15;
    const int kg   = lane >> 4;
    const int pgrp = wid & 1;         // point half (64 pts)
    const int cgrp = wid >> 1;        // code group 0..7 (32 codes per pass)
    const int ptBlock = blockIdx.x * BM;

    // ---- stage x tile: split to f16 hi/lo in LDS + |x|^2 partials ----
    const float4* xg4 = reinterpret_cast<const float4*>(x);
    #pragma unroll
    for (int it = 0; it < 4; ++it) {
        int u = it * 1024 + tid, row = u >> 5, c8 = u & 31;   // 4096 h8 units
        float4 a = xg4[(size_t)(ptBlock + row) * 64 + c8 * 2];
        float4 b = xg4[(size_t)(ptBlock + row) * 64 + c8 * 2 + 1];
        h8 hv, lv; cvt_split8(a, b, hv, lv);
        *reinterpret_cast<h8*>(&xh[row * XSTR + c8 * 8]) = hv;
        *reinterpret_cast<h8*>(&xl[row * XSTR + c8 * 8]) = lv;
        float s = ((fmaf(a.x, a.x, a.y * a.y) + fmaf(a.z, a.z, a.w * a.w))
                 + (fmaf(b.x, b.x, b.y * b.y) + fmaf(b.z, b.z, b.w * b.w)));
        #pragma unroll
        for (int m = 1; m <= 16; m <<= 1) s += __shfl_xor(s, m, 64);
        if ((lane & 31) == 0) xsq_s[row] = s;
    }
    if (tid < KC) wsq_s[tid] = wsq[tid];
    __syncthreads();

    // running top-2 per ct (point col = pgrp*64 + ct*16 + l15)
    float sb[4], ss[4];
    int   ib[4], is2[4];
    #pragma unroll
    for (int ct = 0; ct < 4; ++ct) { sb[ct] = INFINITY; ss[ct] = INFINITY; ib[ct] = 0; is2[ct] = 0; }

    #pragma unroll 1
    for (int pass = 0; pass < 2; ++pass) {
        f32x4 acc[2][4];              // [rt (code tile)][ct (point tile)] = 32 regs
        #pragma unroll
        for (int rt = 0; rt < 2; ++rt)
            #pragma unroll
            for (int ct = 0; ct < 4; ++ct)
                acc[rt][ct] = (f32x4){0.f, 0.f, 0.f, 0.f};

        #pragma unroll 1
        for (int dsl = 0; dsl < 8; ++dsl) {
            int boff0 = (pgrp * 64 + l15) * XSTR + dsl * 32 + kg * 8;
            h8 Bh[4];
            #pragma unroll
            for (int ct = 0; ct < 4; ++ct)
                Bh[ct] = *reinterpret_cast<const h8*>(&xh[boff0 + ct * 16 * XSTR]);
            h8 Ah[2], Al[2];
            #pragma unroll
            for (int rt = 0; rt < 2; ++rt) {
                int ctg = pass * 16 + cgrp * 2 + rt;
                size_t aoff = ((size_t)ctg * 8 + dsl) * 512 + kg * 128 + l15 * 8;
                Ah[rt] = *reinterpret_cast<const h8*>(wfh + aoff);
                Al[rt] = *reinterpret_cast<const h8*>(wfl + aoff);
            }
            #pragma unroll
            for (int rt = 0; rt < 2; ++rt)
                #pragma unroll
                for (int ct = 0; ct < 4; ++ct)
                    acc[rt][ct] = __builtin_amdgcn_mfma_f32_16x16x32_f16(Ah[rt], Bh[ct], acc[rt][ct], 0, 0, 0);
            #pragma unroll
            for (int rt = 0; rt < 2; ++rt)
                #pragma unroll
                for (int ct = 0; ct < 4; ++ct)
                    acc[rt][ct] = __builtin_amdgcn_mfma_f32_16x16x32_f16(Al[rt], Bh[ct], acc[rt][ct], 0, 0, 0);
            h8 Bl[4];                 // loaded late so Bh regs can die first
            #pragma unroll
            for (int ct = 0; ct < 4; ++ct)
                Bl[ct] = *reinterpret_cast<const h8*>(&xl[boff0 + ct * 16 * XSTR]);
            #pragma unroll
            for (int rt = 0; rt < 2; ++rt)
                #pragma unroll
                for (int ct = 0; ct < 4; ++ct)
                    acc[rt][ct] = __builtin_amdgcn_mfma_f32_16x16x32_f16(Ah[rt], Bl[ct], acc[rt][ct], 0, 0, 0);
        }

        // in-lane scan into running top-2; codes ascend over (pass, rt, r)
        #pragma unroll
        for (int rt = 0; rt < 2; ++rt) {
            #pragma unroll
            for (int r = 0; r < 4; ++r) {
                int cc = pass * 256 + cgrp * 32 + rt * 16 + kg * 4 + r;
                float wq = wsq_s[cc];
                #pragma unroll
                for (int ct = 0; ct < 4; ++ct) {
                    float d = wq - 2.f * acc[rt][ct][r];
                    if (d < sb[ct] || (d == sb[ct] && cc < ib[ct])) {
                        ss[ct] = sb[ct]; is2[ct] = ib[ct]; sb[ct] = d; ib[ct] = cc;
                    } else if (d < ss[ct] || (d == ss[ct] && cc < is2[ct])) {
                        ss[ct] = d; is2[ct] = cc;
                    }
                }
            }
        }
    }

    // cross-lane merge over kg groups: masks 16, 32
    #pragma unroll
    for (int ct = 0; ct < 4; ++ct) {
        #pragma unroll
        for (int m = 16; m <= 32; m <<= 1) {
            float ob1 = __shfl_xor(sb[ct], m, 64), ob2 = __shfl_xor(ss[ct], m, 64);
            int   oi1 = __shfl_xor(ib[ct], m, 64), oi2 = __shfl_xor(is2[ct], m, 64);
            merge_top2(sb[ct], ib[ct], ss[ct], is2[ct], ob1, oi1, ob2, oi2);
        }
    }
    __syncthreads();                  // all xh/xl reads done -> safe to alias

    if (kg == 0) {
        #pragma unroll
        for (int ct = 0; ct < 4; ++ct) {
            int p = pgrp * 64 + ct * 16 + l15;
            red_b[cgrp * BM + p] = sb[ct];  red_s[cgrp * BM + p] = ss[ct];
            red_ib[cgrp * BM + p] = ib[ct]; red_is[cgrp * BM + p] = is2[ct];
        }
    }
    __syncthreads();

    // cross-group merge + exact top-2 recheck + enc_idx + hist + mse partials
    if (tid < BM) {
        float b = red_b[tid], s = red_s[tid];
        int  bi = red_ib[tid], si = red_is[tid];
        #pragma unroll
        for (int g = 1; g < 8; ++g)
            merge_top2(b, bi, s, si, red_b[g * BM + tid], red_ib[g * BM + tid],
                       red_s[g * BM + tid], red_is[g * BM + tid]);

        if (s - b < EPS) {            // near-tie: exact fp32 resolve of the two candidates (rare)
            const float* xrp = x + (size_t)(ptBlock + tid) * DIM;
            float d1 = exact_dist(xrp, w, bi, wsq_s[bi]);
            float d2 = exact_dist(xrp, w, si, wsq_s[si]);
            if (d2 < d1 || (d2 == d1 && si < bi)) { bi = si; b = d2; } else { b = d1; }
        }
        bidx_s[tid] = bi;
        out[EOFF + ptBlock + tid] = (float)bi;
        atomicAdd(&hist[bi], 1);

        float msum = xsq_s[tid] + b;  // |x-w|^2 (coarse err ~2e-5, mse-safe)
        #pragma unroll
        for (int m = 32; m; m >>= 1) msum += __shfl_xor(msum, m, 64);
        if (lane == 0) wsum[wid] = msum;   // wid in {0,1}
    }
    __syncthreads();
    if (tid == 0) atomicAdd(mse_acc, (double)(wsum[0] + wsum[1]));

    // fused quantized write: wave per row, 1 KB contiguous R/W (L2-hot w rows)
    {
        const float4* wg4 = reinterpret_cast<const float4*>(w);
        float4* q4 = reinterpret_cast<float4*>(out + QOFF);
        #pragma unroll
        for (int r8 = 0; r8 < 8; ++r8) {
            int row = r8 * 16 + wid;
            int cc = bidx_s[row];
            q4[(size_t)(ptBlock + row) * 64 + lane] = wg4[(size_t)cc * 64 + lane];
        }
    }
}

// ---------------- PROBE: staging + A-load/B-read/MFMA core ONLY (ablation) ----------------
// Identical staging + dsl loop as som_main; scan/merge/recheck/quant removed.
// Keep-alives prevent DCE (rule #17). Writes only dead scratch (g region, &255).
// Grid = 3*NBLK so this dispatch tops the duration table: core_time = dur/3.
__global__ __launch_bounds__(1024) void som_probe(const float* __restrict__ x,
                                                  const _Float16* __restrict__ wfh,
                                                  const _Float16* __restrict__ wfl,
                                                  const float* __restrict__ wsq,
                                                  float* __restrict__ scratch)
{
    alignas(16) __shared__ _Float16 xh[BM * XSTR];
    alignas(16) __shared__ _Float16 xl[BM * XSTR];
    __shared__ float wsq_s[KC];
    __shared__ float xsq_s[BM];

    const int tid  = threadIdx.x;
    const int lane = tid & 63;
    const int wid  = tid >> 6;
    const int l15  = lane & 15;
    const int kg   = lane >> 4;
    const int pgrp = wid & 1;
    const int cgrp = wid >> 1;
    const int ptBlock = (blockIdx.x & (NBLK - 1)) * BM;

    const float4* xg4 = reinterpret_cast<const float4*>(x);
    #pragma unroll
    for (int it = 0; it < 4; ++it) {
        int u = it * 1024 + tid, row = u >> 5, c8 = u & 31;
        float4 a = xg4[(size_t)(ptBlock + row) * 64 + c8 * 2];
        float4 b = xg4[(size_t)(ptBlock + row) * 64 + c8 * 2 + 1];
        h8 hv, lv; cvt_split8(a, b, hv, lv);
        *reinterpret_cast<h8*>(&xh[row * XSTR + c8 * 8]) = hv;
        *reinterpret_cast<h8*>(&xl[row * XSTR + c8 * 8]) = lv;
        float s = ((fmaf(a.x, a.x, a.y * a.y) + fmaf(a.z, a.z, a.w * a.w))
                 + (fmaf(b.x, b.x, b.y * b.y) + fmaf(b.z, b.z, b.w * b.w)));
        #pragma unroll
        for (int m = 1; m <= 16; m <<= 1) s += __shfl_xor(s, m, 64);
        if ((lane & 31) == 0) xsq_s[row] = s;
    }
    if (tid < KC) wsq_s[tid] = wsq[tid];
    __syncthreads();

    float keep = 0.f;
    #pragma unroll 1
    for (int pass = 0; pass < 2; ++pass) {
        f32x4 acc[2][4];
        #pragma unroll
        for (int rt = 0; rt < 2; ++rt)
            #pragma unroll
            for (int ct = 0; ct < 4; ++ct)
                acc[rt][ct] = (f32x4){0.f, 0.f, 0.f, 0.f};

        #pragma unroll 1
        for (int dsl = 0; dsl < 8; ++dsl) {
            int boff0 = (pgrp * 64 + l15) * XSTR + dsl * 32 + kg * 8;
            h8 Bh[4];
            #pragma unroll
            for (int ct = 0; ct < 4; ++ct)
                Bh[ct] = *reinterpret_cast<const h8*>(&xh[boff0 + ct * 16 * XSTR]);
            h8 Ah[2], Al[2];
            #pragma unroll
            for (int rt = 0; rt < 2; ++rt) {
                int ctg = pass * 16 + cgrp * 2 + rt;
                size_t aoff = ((size_t)ctg * 8 + dsl) * 512 + kg * 128 + l15 * 8;
                Ah[rt] = *reinterpret_cast<const h8*>(wfh + aoff);
                Al[rt] = *reinterpret_cast<const h8*>(wfl + aoff);
            }
            #pragma unroll
            for (int rt = 0; rt < 2; ++rt)
                #pragma unroll
                for (int ct = 0; ct < 4; ++ct)
                    acc[rt][ct] = __builtin_amdgcn_mfma_f32_16x16x32_f16(Ah[rt], Bh[ct], acc[rt][ct], 0, 0, 0);
            #pragma unroll
            for (int rt = 0; rt < 2; ++rt)
                #pragma unroll
                for (int ct = 0; ct < 4; ++ct)
                    acc[rt][ct] = __builtin_amdgcn_mfma_f32_16x16x32_f16(Al[rt], Bh[ct], acc[rt][ct], 0, 0, 0);
            h8 Bl[4];
            #pragma unroll
            for (int ct = 0; ct < 4; ++ct)
                Bl[ct] = *reinterpret_cast<const h8*>(&xl[boff0 + ct * 16 * XSTR]);
            #pragma unroll
            for (int rt = 0; rt < 2; ++rt)
                #pragma unroll
                for (int ct = 0; ct < 4; ++ct)
                    acc[rt][ct] = __builtin_amdgcn_mfma_f32_16x16x32_f16(Ah[rt], Bl[ct], acc[rt][ct], 0, 0, 0);
        }
        // fold acc into keep (keeps all MFMAs live, ~32 VALU — negligible)
        #pragma unroll
        for (int rt = 0; rt < 2; ++rt)
            #pragma unroll
            for (int ct = 0; ct < 4; ++ct)
                keep += acc[rt][ct][0] + acc[rt][ct][3];
    }

    keep += xsq_s[tid & 127] + wsq_s[tid & 511];
    asm volatile("" :: "v"(keep));    // anti-DCE
    if (tid == 0) scratch[blockIdx.x & 255] = keep;
}

// ---------------- g[j] = sum_k bmat[j,k] * (wsq[k] + wsq[j] - 2 w_j.w_k) ----------------
__global__ __launch_bounds__(256) void som_g(const float* __restrict__ w,
                                             const float* __restrict__ bmat,
                                             const float* __restrict__ wsq,
                                             float* __restrict__ g)
{
    __shared__ float wj[DIM];
    __shared__ float psum[4];
    const int j = blockIdx.x;
    const int tid = threadIdx.x;
    wj[tid] = w[(size_t)j * DIM + tid];
    __syncthreads();
    const float wsqj = wsq[j];
    float sum = 0.f;
    for (int k = tid; k < KC; k += 256) {
        const float* wk = &w[(size_t)k * DIM];
        float d0 = 0.f, d1 = 0.f, d2 = 0.f, d3 = 0.f;
        #pragma unroll 4
        for (int d = 0; d < DIM; d += 4) {
            d0 = fmaf(wj[d + 0], wk[d + 0], d0);
            d1 = fmaf(wj[d + 1], wk[d + 1], d1);
            d2 = fmaf(wj[d + 2], wk[d + 2], d2);
            d3 = fmaf(wj[d + 3], wk[d + 3], d3);
        }
        float dot = (d0 + d1) + (d2 + d3);
        float t = wsq[k] + wsqj - 2.f * dot;
        sum = fmaf(bmat[(size_t)j * KC + k], t, sum);
    }
    #pragma unroll
    for (int m = 32; m; m >>= 1) sum += __shfl_xor(sum, m, 64);
    int lane = tid & 63, wid = tid >> 6;
    if (lane == 0) psum[wid] = sum;
    __syncthreads();
    if (tid == 0) g[j] = (psum[0] + psum[1]) + (psum[2] + psum[3]);
}

// ---------------- final: perplexity + loss ----------------
__global__ __launch_bounds__(512) void som_final(const int* __restrict__ hist,
                                                 const float* __restrict__ g,
                                                 const double* __restrict__ mse_acc,
                                                 float* __restrict__ out)
{
    __shared__ float e_part[8], k_part[8];
    const int tid = threadIdx.x;
    int cnt = hist[tid];
    float p = (float)cnt / (float)NPTS;
    float ent = -p * logf(p + 1e-10f);
    float koh = (float)cnt * g[tid];
    #pragma unroll
    for (int m = 32; m; m >>= 1) {
        ent += __shfl_xor(ent, m, 64);
        koh += __shfl_xor(koh, m, 64);
    }
    int lane = tid & 63, wid = tid >> 6;
    if (lane == 0) { e_part[wid] = ent; k_part[wid] = koh; }
    __syncthreads();
    if (tid == 0) {
        float es = 0.f, ks = 0.f;
        #pragma unroll
        for (int i = 0; i < 8; ++i) { es += e_part[i]; ks += k_part[i]; }
        float mse = (float)(*mse_acc / (double)(NPTS * (size_t)DIM));
        out[0] = fmaf(1.25f, mse, ks / (float)NPTS);
        out[PIDX] = expf(es);
    }
}

extern "C" void kernel_launch(void* const* d_in, const int* in_sizes, int n_in,
                              void* d_out, int out_size, void* d_ws, size_t ws_size,
                              hipStream_t stream) {
    const float* x    = (const float*)d_in[0];
    const float* w    = (const float*)d_in[1];
    const float* bmat = (const float*)d_in[2];
    float* out = (float*)d_out;

    _Float16* wfh = (_Float16*)d_ws;                         // 256 KB
    _Float16* wfl = wfh + 131072;                            // 256 KB
    float*  wsq  = (float*)((char*)d_ws + 524288);
    float*  g    = (float*)((char*)d_ws + 526336);
    int*    hist = (int*)((char*)d_ws + 528384);
    double* mse  = (double*)((char*)d_ws + 530432);

    som_wsq  <<<2, 256, 0, stream>>>(w, wsq, hist, mse);
    som_conv <<<64, 256, 0, stream>>>(w, wfh, wfl);
    som_main <<<NBLK, 1024, 0, stream>>>(x, w, wfh, wfl, out, wsq, hist, mse);
    som_g    <<<KC, 256, 0, stream>>>(w, bmat, wsq, g);
    som_final<<<1, KC, 0, stream>>>(hist, g, mse, out);
    // ablation probe: runs last, writes only dead scratch (g region). 3x grid so
    // its duration tops the rocprof table; core phase time = probe_dur / 3.
    som_probe<<<3 * NBLK, 1024, 0, stream>>>(x, wfh, wfl, wsq, g);
}

// Round 16
// 180.160 us; speedup vs baseline: 1.6554x; 1.6554x over previous
//
#include <hip/hip_runtime.h>
#include <hip/hip_bf16.h>
#include <hip/hip_fp16.h>
#include <math.h>

// Problem constants
#define NPTS 65536
#define DIM  256
#define KC   512

// som_main geometry
#define BM    128                 // points per block
#define NBLK  (NPTS / BM)         // 512 blocks
#define XSTR  264                 // x LDS row stride in halfs (528 B, 16B-aligned)
#define EPS   0.01f               // split-fp16 coarse err ~2e-5 -> huge margin (r9-proven)

// d_out layout (floats): [0]=loss, [1..1+16777216)=quantized, [16777217]=perplexity,
// [16777218..+65536)=enc_idx (as float)
#define QOFF  1
#define PIDX  16777217
#define EOFF  16777218

// d_ws layout:
//   wfh  _Float16[131072]  @ 0        (256 KB)
//   wfl  _Float16[131072]  @ 262144   (256 KB)
//   wsq  float[512]        @ 524288
//   g    float[512]        @ 526336
//   hist int[512]          @ 528384
//   mse  double            @ 530432
//   xsq  float[65536]      @ 532480   (256 KB)   [split path only]
//   cand float4[8*65536]   @ 794624   (8 MB)     [split path only]
#define XSQ_OFF   532480
#define CAND_OFF  794624
#define WS_NEEDED (CAND_OFF + (size_t)8 * 65536 * 16)

typedef _Float16 h8    __attribute__((ext_vector_type(8)));
typedef float    f32x4 __attribute__((ext_vector_type(4)));

__device__ inline void cvt_split8(float4 a, float4 b, h8& hv, h8& lv) {
    float f[8] = {a.x, a.y, a.z, a.w, b.x, b.y, b.z, b.w};
    #pragma unroll
    for (int i = 0; i < 8; ++i) {
        _Float16 h = (_Float16)f[i];
        hv[i] = h;
        lv[i] = (_Float16)(f[i] - (float)h);
    }
}

// merge top-2 set with another top-2 set; first-index tie-break on best (r5-verified)
__device__ inline void merge_top2(float& b1, int& i1, float& b2, int& i2,
                                  float ob1, int oi1, float ob2, int oi2) {
    bool ow = (ob1 < b1) || (ob1 == b1 && oi1 < i1);
    float lb = ow ? b1 : ob1; int li = ow ? i1 : oi1;
    if (ow) { b1 = ob1; i1 = oi1; }
    float c2 = b2; int ci = i2;
    if (ob2 < c2 || (ob2 == c2 && oi2 < ci)) { c2 = ob2; ci = oi2; }
    if (lb  < c2 || (lb  == c2 && li  < ci)) { c2 = lb;  ci = li;  }
    b2 = c2; i2 = ci;
}

// exact fp32 distance (same accumulation family as the r3-passing kernel)
__device__ inline float exact_dist(const float* __restrict__ xr,
                                   const float* __restrict__ w, int c, float wsqc) {
    const float* wr = w + (size_t)c * DIM;
    float d0 = 0.f, d1 = 0.f, d2 = 0.f, d3 = 0.f;
    #pragma unroll 4
    for (int d = 0; d < DIM; d += 4) {
        d0 = fmaf(xr[d + 0], wr[d + 0], d0);
        d1 = fmaf(xr[d + 1], wr[d + 1], d1);
        d2 = fmaf(xr[d + 2], wr[d + 2], d2);
        d3 = fmaf(xr[d + 3], wr[d + 3], d3);
    }
    return wsqc - 2.f * ((d0 + d1) + (d2 + d3));
}

// ---------------- wsq: |w_k|^2 (exact r3 order) + zero hist/mse ----------------
__global__ __launch_bounds__(256) void som_wsq(const float* __restrict__ w,
                                               float* __restrict__ wsq,
                                               int* __restrict__ hist,
                                               double* __restrict__ mse_acc)
{
    int k = blockIdx.x * 256 + threadIdx.x;   // grid = 2
    const float4* r = reinterpret_cast<const float4*>(w + (size_t)k * DIM);
    float s0 = 0.f, s1 = 0.f, s2 = 0.f, s3 = 0.f;
    #pragma unroll 8
    for (int q = 0; q < DIM / 4; ++q) {
        float4 v = r[q];
        s0 = fmaf(v.x, v.x, s0);
        s1 = fmaf(v.y, v.y, s1);
        s2 = fmaf(v.z, v.z, s2);
        s3 = fmaf(v.w, v.w, s3);
    }
    wsq[k] = (s0 + s1) + (s2 + s3);
    hist[k] = 0;
    if (k == 0) *mse_acc = 0.0;
}

// ---------------- conv: split-f16 conversion of w into fragment order (r9 layout) ----------------
__global__ __launch_bounds__(256) void som_conv(const float* __restrict__ w,
                                                _Float16* __restrict__ wfh,
                                                _Float16* __restrict__ wfl)
{
    const int tid = threadIdx.x;
    const int row = blockIdx.x * 8 + (tid >> 5);   // code row; grid = 64
    const int g   = tid & 31;                      // h8 unit within row
    const float4* r = reinterpret_cast<const float4*>(w + (size_t)row * DIM);
    float4 a = r[g * 2], b = r[g * 2 + 1];
    h8 hv, lv; cvt_split8(a, b, hv, lv);
    int dsl = g >> 2, kg = g & 3;
    int ctg = row >> 4, l15 = row & 15;
    size_t off = (((size_t)(ctg * 8 + dsl)) * 4 + kg) * 128 + l15 * 8;
    *reinterpret_cast<h8*>(wfh + off) = hv;
    *reinterpret_cast<h8*>(wfl + off) = lv;
}

// ---------------- main v2: core + scan + butterfly; candidates -> global (no tail) ----------------
__global__ __launch_bounds__(1024) void som_main2(const float* __restrict__ x,
                                                  const _Float16* __restrict__ wfh,
                                                  const _Float16* __restrict__ wfl,
                                                  const float* __restrict__ wsq,
                                                  float4* __restrict__ cand,
                                                  float* __restrict__ xsq_g)
{
    alignas(16) __shared__ _Float16 xh[BM * XSTR];   // 67,584 B
    alignas(16) __shared__ _Float16 xl[BM * XSTR];   // 67,584 B
    __shared__ float wsq_s[KC];                      // 2 KB

    const int tid  = threadIdx.x;
    const int lane = tid & 63;
    const int wid  = tid >> 6;        // 0..15
    const int l15  = lane & 15;
    const int kg   = lane >> 4;
    const int pgrp = wid & 1;         // point half (64 pts)
    const int cgrp = wid >> 1;        // code group 0..7
    const int ptBlock = blockIdx.x * BM;

    // ---- stage x tile: split to f16 hi/lo in LDS + |x|^2 -> global ----
    const float4* xg4 = reinterpret_cast<const float4*>(x);
    #pragma unroll
    for (int it = 0; it < 4; ++it) {
        int u = it * 1024 + tid, row = u >> 5, c8 = u & 31;
        float4 a = xg4[(size_t)(ptBlock + row) * 64 + c8 * 2];
        float4 b = xg4[(size_t)(ptBlock + row) * 64 + c8 * 2 + 1];
        h8 hv, lv; cvt_split8(a, b, hv, lv);
        *reinterpret_cast<h8*>(&xh[row * XSTR + c8 * 8]) = hv;
        *reinterpret_cast<h8*>(&xl[row * XSTR + c8 * 8]) = lv;
        float s = ((fmaf(a.x, a.x, a.y * a.y) + fmaf(a.z, a.z, a.w * a.w))
                 + (fmaf(b.x, b.x, b.y * b.y) + fmaf(b.z, b.z, b.w * b.w)));
        #pragma unroll
        for (int m = 1; m <= 16; m <<= 1) s += __shfl_xor(s, m, 64);
        if ((lane & 31) == 0) xsq_g[ptBlock + row] = s;
    }
    if (tid < KC) wsq_s[tid] = wsq[tid];
    __syncthreads();                  // the only barrier

    float sb[4], ss[4];
    int   ib[4], is2[4];
    #pragma unroll
    for (int ct = 0; ct < 4; ++ct) { sb[ct] = INFINITY; ss[ct] = INFINITY; ib[ct] = 0; is2[ct] = 0; }

    #pragma unroll 1
    for (int pass = 0; pass < 2; ++pass) {
        f32x4 acc[2][4];
        #pragma unroll
        for (int rt = 0; rt < 2; ++rt)
            #pragma unroll
            for (int ct = 0; ct < 4; ++ct)
                acc[rt][ct] = (f32x4){0.f, 0.f, 0.f, 0.f};

        #pragma unroll 1
        for (int dsl = 0; dsl < 8; ++dsl) {
            int boff0 = (pgrp * 64 + l15) * XSTR + dsl * 32 + kg * 8;
            h8 Bh[4];
            #pragma unroll
            for (int ct = 0; ct < 4; ++ct)
                Bh[ct] = *reinterpret_cast<const h8*>(&xh[boff0 + ct * 16 * XSTR]);
            h8 Ah[2], Al[2];
            #pragma unroll
            for (int rt = 0; rt < 2; ++rt) {
                int ctg = pass * 16 + cgrp * 2 + rt;
                size_t aoff = ((size_t)ctg * 8 + dsl) * 512 + kg * 128 + l15 * 8;
                Ah[rt] = *reinterpret_cast<const h8*>(wfh + aoff);
                Al[rt] = *reinterpret_cast<const h8*>(wfl + aoff);
            }
            #pragma unroll
            for (int rt = 0; rt < 2; ++rt)
                #pragma unroll
                for (int ct = 0; ct < 4; ++ct)
                    acc[rt][ct] = __builtin_amdgcn_mfma_f32_16x16x32_f16(Ah[rt], Bh[ct], acc[rt][ct], 0, 0, 0);
            #pragma unroll
            for (int rt = 0; rt < 2; ++rt)
                #pragma unroll
                for (int ct = 0; ct < 4; ++ct)
                    acc[rt][ct] = __builtin_amdgcn_mfma_f32_16x16x32_f16(Al[rt], Bh[ct], acc[rt][ct], 0, 0, 0);
            h8 Bl[4];
            #pragma unroll
            for (int ct = 0; ct < 4; ++ct)
                Bl[ct] = *reinterpret_cast<const h8*>(&xl[boff0 + ct * 16 * XSTR]);
            #pragma unroll
            for (int rt = 0; rt < 2; ++rt)
                #pragma unroll
                for (int ct = 0; ct < 4; ++ct)
                    acc[rt][ct] = __builtin_amdgcn_mfma_f32_16x16x32_f16(Ah[rt], Bl[ct], acc[rt][ct], 0, 0, 0);
        }

        // in-lane scan into running top-2; codes ascend over (pass, rt, r)
        #pragma unroll
        for (int rt = 0; rt < 2; ++rt) {
            #pragma unroll
            for (int r = 0; r < 4; ++r) {
                int cc = pass * 256 + cgrp * 32 + rt * 16 + kg * 4 + r;
                float wq = wsq_s[cc];
                #pragma unroll
                for (int ct = 0; ct < 4; ++ct) {
                    float d = wq - 2.f * acc[rt][ct][r];
                    if (d < sb[ct] || (d == sb[ct] && cc < ib[ct])) {
                        ss[ct] = sb[ct]; is2[ct] = ib[ct]; sb[ct] = d; ib[ct] = cc;
                    } else if (d < ss[ct] || (d == ss[ct] && cc < is2[ct])) {
                        ss[ct] = d; is2[ct] = cc;
                    }
                }
            }
        }
    }

    // cross-lane butterfly over kg groups: masks 16, 32 (all lanes end with result)
    #pragma unroll
    for (int ct = 0; ct < 4; ++ct) {
        #pragma unroll
        for (int m = 16; m <= 32; m <<= 1) {
            float ob1 = __shfl_xor(sb[ct], m, 64), ob2 = __shfl_xor(ss[ct], m, 64);
            int   oi1 = __shfl_xor(ib[ct], m, 64), oi2 = __shfl_xor(is2[ct], m, 64);
            merge_top2(sb[ct], ib[ct], ss[ct], is2[ct], ob1, oi1, ob2, oi2);
        }
    }
    // write per-group candidates: group-major cand[cgrp][point] (coalesced 256B runs)
    if (kg == 0) {
        #pragma unroll
        for (int ct = 0; ct < 4; ++ct) {
            int p = ptBlock + pgrp * 64 + ct * 16 + l15;
            float4 v;
            v.x = sb[ct]; v.y = ss[ct];
            v.z = __int_as_float(ib[ct]); v.w = __int_as_float(is2[ct]);
            cand[(cgrp << 16) + p] = v;
        }
    }
}

// ---------------- tail: merge candidates + recheck + outputs + quant ----------------
// 256 blocks x 256 thr; thread = one point, then block-cooperative quant.
__global__ __launch_bounds__(256) void som_tail(const float* __restrict__ x,
                                                const float* __restrict__ w,
                                                const float4* __restrict__ cand,
                                                const float* __restrict__ xsq_g,
                                                const float* __restrict__ wsq,
                                                float* __restrict__ out,
                                                int* __restrict__ hist,
                                                double* __restrict__ mse_acc)
{
    __shared__ float wsq_s[KC];
    __shared__ int   bidx_s[256];
    __shared__ float wsum[4];

    const int tid  = threadIdx.x;
    const int lane = tid & 63;
    const int wid  = tid >> 6;
    const int p    = blockIdx.x * 256 + tid;

    wsq_s[tid] = wsq[tid];
    wsq_s[256 + tid] = wsq[256 + tid];

    // merge 8 per-group top-2 sets (same chain order as r14: g ascending)
    float4 c0 = cand[p];
    float b = c0.x, s = c0.y;
    int  bi = __float_as_int(c0.z), si = __float_as_int(c0.w);
    #pragma unroll
    for (int g = 1; g < 8; ++g) {
        float4 cg = cand[(g << 16) + p];
        merge_top2(b, bi, s, si, cg.x, __float_as_int(cg.z), cg.y, __float_as_int(cg.w));
    }
    __syncthreads();                  // wsq_s ready (needed only for rare recheck)

    if (s - b < EPS) {                // near-tie: exact fp32 resolve (rare)
        const float* xrp = x + (size_t)p * DIM;
        float d1 = exact_dist(xrp, w, bi, wsq_s[bi]);
        float d2 = exact_dist(xrp, w, si, wsq_s[si]);
        if (d2 < d1 || (d2 == d1 && si < bi)) { bi = si; b = d2; } else { b = d1; }
    }
    bidx_s[tid] = bi;
    out[EOFF + p] = (float)bi;
    atomicAdd(&hist[bi], 1);

    float msum = xsq_g[p] + b;        // |x-w|^2 (coarse err ~2e-5, mse-safe)
    #pragma unroll
    for (int m = 32; m; m >>= 1) msum += __shfl_xor(msum, m, 64);
    if (lane == 0) wsum[wid] = msum;
    __syncthreads();                  // wsum + bidx_s ready
    if (tid == 0)
        atomicAdd(mse_acc, (double)((wsum[0] + wsum[1]) + (wsum[2] + wsum[3])));

    // quant: wave per row, 64 rows/wave, 1 KB contiguous R/W (w rows L2-hot)
    const float4* wg4 = reinterpret_cast<const float4*>(w);
    float4* q4 = reinterpret_cast<float4*>(out + QOFF);
    const size_t pBase = (size_t)blockIdx.x * 256;
    #pragma unroll 4
    for (int it = 0; it < 64; ++it) {
        int row = it * 4 + wid;
        int cc = bidx_s[row];
        q4[(pBase + row) * 64 + lane] = wg4[(size_t)cc * 64 + lane];
    }
}

// ---------------- FALLBACK: r14 monolithic som_main (proven, 125 us) ----------------
__global__ __launch_bounds__(1024) void som_main_fused(const float* __restrict__ x,
                                                       const float* __restrict__ w,
                                                       const _Float16* __restrict__ wfh,
                                                       const _Float16* __restrict__ wfl,
                                                       float* __restrict__ out,
                                                       const float* __restrict__ wsq,
                                                       int* __restrict__ hist,
                                                       double* __restrict__ mse_acc)
{
    alignas(16) __shared__ _Float16 xh[BM * XSTR];
    alignas(16) __shared__ _Float16 xl[BM * XSTR];
    __shared__ float wsq_s[KC];
    __shared__ float xsq_s[BM];
    __shared__ float wsum[2];

    float* red_b  = reinterpret_cast<float*>(xh);
    float* red_s  = red_b + 8 * BM;
    int*   red_ib = reinterpret_cast<int*>(red_s + 8 * BM);
    int*   red_is = red_ib + 8 * BM;
    int*   bidx_s = reinterpret_cast<int*>(xl);

    const int tid  = threadIdx.x;
    const int lane = tid & 63;
    const int wid  = tid >> 6;
    const int l15  = lane & 15;
    const int kg   = lane >> 4;
    const int pgrp = wid & 1;
    const int cgrp = wid >> 1;
    const int ptBlock = blockIdx.x * BM;

    const float4* xg4 = reinterpret_cast<const float4*>(x);
    #pragma unroll
    for (int it = 0; it < 4; ++it) {
        int u = it * 1024 + tid, row = u >> 5, c8 = u & 31;
        float4 a = xg4[(size_t)(ptBlock + row) * 64 + c8 * 2];
        float4 b = xg4[(size_t)(ptBlock + row) * 64 + c8 * 2 + 1];
        h8 hv, lv; cvt_split8(a, b, hv, lv);
        *reinterpret_cast<h8*>(&xh[row * XSTR + c8 * 8]) = hv;
        *reinterpret_cast<h8*>(&xl[row * XSTR + c8 * 8]) = lv;
        float s = ((fmaf(a.x, a.x, a.y * a.y) + fmaf(a.z, a.z, a.w * a.w))
                 + (fmaf(b.x, b.x, b.y * b.y) + fmaf(b.z, b.z, b.w * b.w)));
        #pragma unroll
        for (int m = 1; m <= 16; m <<= 1) s += __shfl_xor(s, m, 64);
        if ((lane & 31) == 0) xsq_s[row] = s;
    }
    if (tid < KC) wsq_s[tid] = wsq[tid];
    __syncthreads();

    float sb[4], ss[4];
    int   ib[4], is2[4];
    #pragma unroll
    for (int ct = 0; ct < 4; ++ct) { sb[ct] = INFINITY; ss[ct] = INFINITY; ib[ct] = 0; is2[ct] = 0; }

    #pragma unroll 1
    for (int pass = 0; pass < 2; ++pass) {
        f32x4 acc[2][4];
        #pragma unroll
        for (int rt = 0; rt < 2; ++rt)
            #pragma unroll
            for (int ct = 0; ct < 4; ++ct)
                acc[rt][ct] = (f32x4){0.f, 0.f, 0.f, 0.f};

        #pragma unroll 1
        for (int dsl = 0; dsl < 8; ++dsl) {
            int boff0 = (pgrp * 64 + l15) * XSTR + dsl * 32 + kg * 8;
            h8 Bh[4];
            #pragma unroll
            for (int ct = 0; ct < 4; ++ct)
                Bh[ct] = *reinterpret_cast<const h8*>(&xh[boff0 + ct * 16 * XSTR]);
            h8 Ah[2], Al[2];
            #pragma unroll
            for (int rt = 0; rt < 2; ++rt) {
                int ctg = pass * 16 + cgrp * 2 + rt;
                size_t aoff = ((size_t)ctg * 8 + dsl) * 512 + kg * 128 + l15 * 8;
                Ah[rt] = *reinterpret_cast<const h8*>(wfh + aoff);
                Al[rt] = *reinterpret_cast<const h8*>(wfl + aoff);
            }
            #pragma unroll
            for (int rt = 0; rt < 2; ++rt)
                #pragma unroll
                for (int ct = 0; ct < 4; ++ct)
                    acc[rt][ct] = __builtin_amdgcn_mfma_f32_16x16x32_f16(Ah[rt], Bh[ct], acc[rt][ct], 0, 0, 0);
            #pragma unroll
            for (int rt = 0; rt < 2; ++rt)
                #pragma unroll
                for (int ct = 0; ct < 4; ++ct)
                    acc[rt][ct] = __builtin_amdgcn_mfma_f32_16x16x32_f16(Al[rt], Bh[ct], acc[rt][ct], 0, 0, 0);
            h8 Bl[4];
            #pragma unroll
            for (int ct = 0; ct < 4; ++ct)
                Bl[ct] = *reinterpret_cast<const h8*>(&xl[boff0 + ct * 16 * XSTR]);
            #pragma unroll
            for (int rt = 0; rt < 2; ++rt)
                #pragma unroll
                for (int ct = 0; ct < 4; ++ct)
                    acc[rt][ct] = __builtin_amdgcn_mfma_f32_16x16x32_f16(Ah[rt], Bl[ct], acc[rt][ct], 0, 0, 0);
        }

        #pragma unroll
        for (int rt = 0; rt < 2; ++rt) {
            #pragma unroll
            for (int r = 0; r < 4; ++r) {
                int cc = pass * 256 + cgrp * 32 + rt * 16 + kg * 4 + r;
                float wq = wsq_s[cc];
                #pragma unroll
                for (int ct = 0; ct < 4; ++ct) {
                    float d = wq - 2.f * acc[rt][ct][r];
                    if (d < sb[ct] || (d == sb[ct] && cc < ib[ct])) {
                        ss[ct] = sb[ct]; is2[ct] = ib[ct]; sb[ct] = d; ib[ct] = cc;
                    } else if (d < ss[ct] || (d == ss[ct] && cc < is2[ct])) {
                        ss[ct] = d; is2[ct] = cc;
                    }
                }
            }
        }
    }

    #pragma unroll
    for (int ct = 0; ct < 4; ++ct) {
        #pragma unroll
        for (int m = 16; m <= 32; m <<= 1) {
            float ob1 = __shfl_xor(sb[ct], m, 64), ob2 = __shfl_xor(ss[ct], m, 64);
            int   oi1 = __shfl_xor(ib[ct], m, 64), oi2 = __shfl_xor(is2[ct], m, 64);
            merge_top2(sb[ct], ib[ct], ss[ct], is2[ct], ob1, oi1, ob2, oi2);
        }
    }
    __syncthreads();

    if (kg == 0) {
        #pragma unroll
        for (int ct = 0; ct < 4; ++ct) {
            int p = pgrp * 64 + ct * 16 + l15;
            red_b[cgrp * BM + p] = sb[ct];  red_s[cgrp * BM + p] = ss[ct];
            red_ib[cgrp * BM + p] = ib[ct]; red_is[cgrp * BM + p] = is2[ct];
        }
    }
    __syncthreads();

    if (tid < BM) {
        float b = red_b[tid], s = red_s[tid];
        int  bi = red_ib[tid], si = red_is[tid];
        #pragma unroll
        for (int g = 1; g < 8; ++g)
            merge_top2(b, bi, s, si, red_b[g * BM + tid], red_ib[g * BM + tid],
                       red_s[g * BM + tid], red_is[g * BM + tid]);

        if (s - b < EPS) {
            const float* xrp = x + (size_t)(ptBlock + tid) * DIM;
            float d1 = exact_dist(xrp, w, bi, wsq_s[bi]);
            float d2 = exact_dist(xrp, w, si, wsq_s[si]);
            if (d2 < d1 || (d2 == d1 && si < bi)) { bi = si; b = d2; } else { b = d1; }
        }
        bidx_s[tid] = bi;
        out[EOFF + ptBlock + tid] = (float)bi;
        atomicAdd(&hist[bi], 1);

        float msum = xsq_s[tid] + b;
        #pragma unroll
        for (int m = 32; m; m >>= 1) msum += __shfl_xor(msum, m, 64);
        if (lane == 0) wsum[wid] = msum;
    }
    __syncthreads();
    if (tid == 0) atomicAdd(mse_acc, (double)(wsum[0] + wsum[1]));

    {
        const float4* wg4 = reinterpret_cast<const float4*>(w);
        float4* q4 = reinterpret_cast<float4*>(out + QOFF);
        #pragma unroll
        for (int r8 = 0; r8 < 8; ++r8) {
            int row = r8 * 16 + wid;
            int cc = bidx_s[row];
            q4[(size_t)(ptBlock + row) * 64 + lane] = wg4[(size_t)cc * 64 + lane];
        }
    }
}

// ---------------- g[j] = sum_k bmat[j,k] * (wsq[k] + wsq[j] - 2 w_j.w_k) ----------------
__global__ __launch_bounds__(256) void som_g(const float* __restrict__ w,
                                             const float* __restrict__ bmat,
                                             const float* __restrict__ wsq,
                                             float* __restrict__ g)
{
    __shared__ float wj[DIM];
    __shared__ float psum[4];
    const int j = blockIdx.x;
    const int tid = threadIdx.x;
    wj[tid] = w[(size_t)j * DIM + tid];
    __syncthreads();
    const float wsqj = wsq[j];
    float sum = 0.f;
    for (int k = tid; k < KC; k += 256) {
        const float* wk = &w[(size_t)k * DIM];
        float d0 = 0.f, d1 = 0.f, d2 = 0.f, d3 = 0.f;
        #pragma unroll 4
        for (int d = 0; d < DIM; d += 4) {
            d0 = fmaf(wj[d + 0], wk[d + 0], d0);
            d1 = fmaf(wj[d + 1], wk[d + 1], d1);
            d2 = fmaf(wj[d + 2], wk[d + 2], d2);
            d3 = fmaf(wj[d + 3], wk[d + 3], d3);
        }
        float dot = (d0 + d1) + (d2 + d3);
        float t = wsq[k] + wsqj - 2.f * dot;
        sum = fmaf(bmat[(size_t)j * KC + k], t, sum);
    }
    #pragma unroll
    for (int m = 32; m; m >>= 1) sum += __shfl_xor(sum, m, 64);
    int lane = tid & 63, wid = tid >> 6;
    if (lane == 0) psum[wid] = sum;
    __syncthreads();
    if (tid == 0) g[j] = (psum[0] + psum[1]) + (psum[2] + psum[3]);
}

// ---------------- final: perplexity + loss ----------------
__global__ __launch_bounds__(512) void som_final(const int* __restrict__ hist,
                                                 const float* __restrict__ g,
                                                 const double* __restrict__ mse_acc,
                                                 float* __restrict__ out)
{
    __shared__ float e_part[8], k_part[8];
    const int tid = threadIdx.x;
    int cnt = hist[tid];
    float p = (float)cnt / (float)NPTS;
    float ent = -p * logf(p + 1e-10f);
    float koh = (float)cnt * g[tid];
    #pragma unroll
    for (int m = 32; m; m >>= 1) {
        ent += __shfl_xor(ent, m, 64);
        koh += __shfl_xor(koh, m, 64);
    }
    int lane = tid & 63, wid = tid >> 6;
    if (lane == 0) { e_part[wid] = ent; k_part[wid] = koh; }
    __syncthreads();
    if (tid == 0) {
        float es = 0.f, ks = 0.f;
        #pragma unroll
        for (int i = 0; i < 8; ++i) { es += e_part[i]; ks += k_part[i]; }
        float mse = (float)(*mse_acc / (double)(NPTS * (size_t)DIM));
        out[0] = fmaf(1.25f, mse, ks / (float)NPTS);
        out[PIDX] = expf(es);
    }
}

extern "C" void kernel_launch(void* const* d_in, const int* in_sizes, int n_in,
                              void* d_out, int out_size, void* d_ws, size_t ws_size,
                              hipStream_t stream) {
    const float* x    = (const float*)d_in[0];
    const float* w    = (const float*)d_in[1];
    const float* bmat = (const float*)d_in[2];
    float* out = (float*)d_out;

    _Float16* wfh = (_Float16*)d_ws;                         // 256 KB
    _Float16* wfl = wfh + 131072;                            // 256 KB
    float*  wsq  = (float*)((char*)d_ws + 524288);
    float*  g    = (float*)((char*)d_ws + 526336);
    int*    hist = (int*)((char*)d_ws + 528384);
    double* mse  = (double*)((char*)d_ws + 530432);

    som_wsq  <<<2, 256, 0, stream>>>(w, wsq, hist, mse);
    som_conv <<<64, 256, 0, stream>>>(w, wfh, wfl);

    if (ws_size >= WS_NEEDED) {
        float*  xsq_g = (float*)((char*)d_ws + XSQ_OFF);
        float4* cand  = (float4*)((char*)d_ws + CAND_OFF);
        som_main2<<<NBLK, 1024, 0, stream>>>(x, wfh, wfl, wsq, cand, xsq_g);
        som_tail <<<256, 256, 0, stream>>>(x, w, cand, xsq_g, wsq, out, hist, mse);
    } else {
        som_main_fused<<<NBLK, 1024, 0, stream>>>(x, w, wfh, wfl, out, wsq, hist, mse);
    }

    som_g    <<<KC, 256, 0, stream>>>(w, bmat, wsq, g);
    som_final<<<1, KC, 0, stream>>>(hist, g, mse, out);
}